// Round 1
// baseline (436.574 us; speedup 1.0000x reference)
//
#include <hip/hip_runtime.h>

#define B_  32
#define TK_ 8192
#define H_  256
#define MT  64   // t-tile rows per block

typedef __bf16 bf16_t;
typedef __bf16 bf16x4 __attribute__((ext_vector_type(4)));
typedef __bf16 bf16x8 __attribute__((ext_vector_type(8)));
typedef float  floatx4 __attribute__((ext_vector_type(4)));

__device__ __forceinline__ float tanh_fast(float x) {
    // tanh(x) = 1 - 2/(1+e^{2x});  e^{2x} = exp2(2*log2(e)*x)
    float e = __builtin_amdgcn_exp2f(x * 2.885390081777927f);
    return 1.0f - 2.0f * __builtin_amdgcn_rcpf(e + 1.0f);
}

// ---------------- prep: convert We->bf16, compute dec_fea, zero accumulators ----
__global__ void prep_kernel(const float* __restrict__ s_t_hat,
                            const float* __restrict__ We,
                            const float* __restrict__ Wd,
                            const float* __restrict__ bd,
                            bf16_t* __restrict__ We_bf,
                            float* __restrict__ dec_ws,
                            float* __restrict__ ctx_ws,
                            float* __restrict__ D_ws) {
    int tid = threadIdx.x, blk = blockIdx.x;
    int gid = blk * 256 + tid;              // grid = 256 blocks -> 65536 threads
    We_bf[gid] = (bf16_t)We[gid];           // H*H = 65536 exactly

    if (blk < 32) {
        ctx_ws[gid] = 0.f;                  // 8192 floats
        if (gid < 32) D_ws[gid] = 0.f;
    }
    if (blk >= 32 && blk < 160) {           // 32768 threads: 4 per (b,i)
        int idx  = (blk - 32) * 256 + tid;
        int pair = idx >> 2, q = idx & 3;
        int b = pair >> 8, i = pair & 255;
        const float4* sp = (const float4*)(s_t_hat + b * 2 * H_ + q * 128);
        const float4* wp = (const float4*)(Wd + (size_t)i * 2 * H_ + q * 128);
        float sum = 0.f;
        #pragma unroll 8
        for (int ii = 0; ii < 32; ++ii) {
            float4 a = sp[ii], w = wp[ii];
            sum += a.x * w.x + a.y * w.y + a.z * w.z + a.w * w.w;
        }
        sum += __shfl_xor(sum, 1, 64);
        sum += __shfl_xor(sum, 2, 64);
        if (q == 0) dec_ws[pair] = sum + bd[i];
    }
}

// ---------------- main fused pass: one read of encoder_outputs ----------------
__global__ __launch_bounds__(256, 3) void attn_main(
    const float* __restrict__ enc,
    const float* __restrict__ mask,
    const float* __restrict__ cov,
    const float* __restrict__ wc,
    const float* __restrict__ v,
    const bf16_t* __restrict__ We_bf,
    const float* __restrict__ dec_ws,
    float* __restrict__ ctx_ws,
    float* __restrict__ D_ws,
    float* __restrict__ attn_out) {

    __shared__ __align__(16) bf16_t As[MT * 264];   // 64 rows, pad 256->264
    __shared__ float dec_s[256], wc_s[256], v_s[256];
    __shared__ float cov_s[64], mask_s[64], wexp[64];
    __shared__ float sp[4][64];
    __shared__ float ctxp[4][256];

    const int tid  = threadIdx.x;
    const int b    = blockIdx.y;
    const int t0   = blockIdx.x * MT;
    const int lane = tid & 63, w = tid >> 6;
    const int l15  = lane & 15, l4 = lane >> 4;

    // small stages
    dec_s[tid] = dec_ws[b * 256 + tid];
    wc_s[tid]  = wc[tid];
    v_s[tid]   = v[tid];
    if (tid < 64)       cov_s[tid]       = cov[(size_t)b * TK_ + t0 + tid];
    else if (tid < 128) mask_s[tid - 64] = mask[(size_t)b * TK_ + t0 + tid - 64];

    // stage enc tile (fp32 -> bf16 LDS), fully coalesced: wave w loads row it*4+w
    const float* encb = enc + ((size_t)b * TK_ + t0) * H_;
    #pragma unroll
    for (int it = 0; it < 16; ++it) {
        int row = it * 4 + w;
        int h   = lane * 4;
        float4 f = *(const float4*)(encb + (size_t)row * H_ + h);
        bf16x4 p;
        p[0] = (bf16_t)f.x; p[1] = (bf16_t)f.y; p[2] = (bf16_t)f.z; p[3] = (bf16_t)f.w;
        *(bf16x4*)(&As[row * 264 + h]) = p;
    }
    __syncthreads();

    // GEMM: wave w covers g in [w*64, w*64+64); acc[mi][ni] 16x16 tiles
    floatx4 acc[4][4];
    #pragma unroll
    for (int mi = 0; mi < 4; ++mi)
        #pragma unroll
        for (int ni = 0; ni < 4; ++ni)
            acc[mi][ni] = (floatx4){0.f, 0.f, 0.f, 0.f};

    const int wbase = w * 64;
    #pragma unroll
    for (int ks = 0; ks < 8; ++ks) {
        int k = ks * 32 + l4 * 8;
        bf16x8 a[4], bq[4];
        #pragma unroll
        for (int mi = 0; mi < 4; ++mi)
            a[mi] = *(const bf16x8*)(&As[(mi * 16 + l15) * 264 + k]);
        #pragma unroll
        for (int ni = 0; ni < 4; ++ni)
            bq[ni] = *(const bf16x8*)(We_bf + (size_t)(wbase + ni * 16 + l15) * 256 + k);
        #pragma unroll
        for (int mi = 0; mi < 4; ++mi)
            #pragma unroll
            for (int ni = 0; ni < 4; ++ni)
                acc[mi][ni] = __builtin_amdgcn_mfma_f32_16x16x32_bf16(
                    a[mi], bq[ni], acc[mi][ni], 0, 0, 0);
    }

    // epilogue: scores.  C layout: col=lane&15, row=(lane>>4)*4+reg
    float decv[4], wcv[4], vv[4];
    #pragma unroll
    for (int ni = 0; ni < 4; ++ni) {
        int g = wbase + ni * 16 + l15;
        decv[ni] = dec_s[g]; wcv[ni] = wc_s[g]; vv[ni] = v_s[g];
    }
    #pragma unroll
    for (int mi = 0; mi < 4; ++mi) {
        #pragma unroll
        for (int r = 0; r < 4; ++r) {
            int t = mi * 16 + l4 * 4 + r;
            float cv = cov_s[t];
            float s = 0.f;
            #pragma unroll
            for (int ni = 0; ni < 4; ++ni) {
                float af = acc[mi][ni][r] + decv[ni] + cv * wcv[ni];
                s += tanh_fast(af) * vv[ni];
            }
            s += __shfl_xor(s, 1, 64);
            s += __shfl_xor(s, 2, 64);
            s += __shfl_xor(s, 4, 64);
            s += __shfl_xor(s, 8, 64);
            if (l15 == 0) sp[w][t] = s;
        }
    }
    __syncthreads();

    if (tid < 64) {
        int t = tid;
        float sc = sp[0][t] + sp[1][t] + sp[2][t] + sp[3][t];
        float wv = __builtin_amdgcn_exp2f(sc * 1.4426950408889634f) * mask_s[t];
        wexp[t] = wv;
        attn_out[(size_t)b * TK_ + t0 + t] = wv;   // unnormalized; finalize divides
        float d = wv;
        d += __shfl_xor(d, 1, 64);  d += __shfl_xor(d, 2, 64);
        d += __shfl_xor(d, 4, 64);  d += __shfl_xor(d, 8, 64);
        d += __shfl_xor(d, 16, 64); d += __shfl_xor(d, 32, 64);
        if (tid == 0) atomicAdd(&D_ws[b], d);
    }
    __syncthreads();

    // ctx partial: wave w handles t in [w*16, w*16+16); lane owns h0..h0+3
    {
        int h0 = lane * 4;
        float c0 = 0, c1 = 0, c2 = 0, c3 = 0;
        #pragma unroll
        for (int tt = 0; tt < 16; ++tt) {
            int t = w * 16 + tt;
            float wv = wexp[t];
            bf16x4 q = *(const bf16x4*)(&As[t * 264 + h0]);
            c0 += wv * (float)q[0];
            c1 += wv * (float)q[1];
            c2 += wv * (float)q[2];
            c3 += wv * (float)q[3];
        }
        ctxp[w][h0 + 0] = c0; ctxp[w][h0 + 1] = c1;
        ctxp[w][h0 + 2] = c2; ctxp[w][h0 + 3] = c3;
    }
    __syncthreads();
    {
        float s = ctxp[0][tid] + ctxp[1][tid] + ctxp[2][tid] + ctxp[3][tid];
        atomicAdd(&ctx_ws[b * 256 + tid], s);
    }
}

// ---------------- finalize: divide by D, write attn / new_cov / c_t ----------
__global__ void finalize_kernel(const float* __restrict__ cov,
                                const float* __restrict__ ctx_ws,
                                const float* __restrict__ D_ws,
                                float* __restrict__ out) {
    int b = blockIdx.y, chunk = blockIdx.x, tid = threadIdx.x;
    float invD = 1.0f / D_ws[b];
    int idx = chunk * 256 + tid;
    size_t gi = (size_t)b * TK_ + idx;
    float* attn = out + 8192;
    float* ncov = out + 8192 + (size_t)B_ * TK_;
    float a = attn[gi] * invD;
    attn[gi] = a;
    float nc = cov[gi] + a;
    ncov[gi] = fminf(fmaxf(nc, 0.f), 1.f);
    if (chunk == 0) out[b * 256 + tid] = ctx_ws[b * 256 + tid] * invD;
}

extern "C" void kernel_launch(void* const* d_in, const int* in_sizes, int n_in,
                              void* d_out, int out_size, void* d_ws, size_t ws_size,
                              hipStream_t stream) {
    const float* s_t_hat = (const float*)d_in[0];
    const float* enc     = (const float*)d_in[1];
    const float* mask    = (const float*)d_in[2];
    const float* cov     = (const float*)d_in[3];
    // d_in[4] = attn_dist_node_to_token: unused by reference
    const float* We      = (const float*)d_in[5];
    const float* Wd      = (const float*)d_in[6];
    const float* bd      = (const float*)d_in[7];
    const float* wc      = (const float*)d_in[8];
    const float* v       = (const float*)d_in[9];
    float* out = (float*)d_out;

    char* ws = (char*)d_ws;
    bf16_t* We_bf = (bf16_t*)ws;                          // 131072 B
    float*  dec_ws = (float*)(ws + 131072);               // 32768 B
    float*  ctx_ws = (float*)(ws + 131072 + 32768);       // 32768 B
    float*  D_ws   = (float*)(ws + 131072 + 65536);       // 128 B

    prep_kernel<<<256, 256, 0, stream>>>(s_t_hat, We, Wd, bd, We_bf, dec_ws, ctx_ws, D_ws);
    attn_main<<<dim3(128, 32), 256, 0, stream>>>(enc, mask, cov, wc, v, We_bf,
                                                 dec_ws, ctx_ws, D_ws, out + 8192);
    finalize_kernel<<<dim3(32, 32), 256, 0, stream>>>(cov, ctx_ws, D_ws, out);
}